// Round 18
// baseline (95.161 us; speedup 1.0000x reference)
//
#include <hip/hip_runtime.h>

#define NN 128
#define CCH 16
#define BB 4
#define HID 128
#define DOUT 128

typedef float f32x4 __attribute__((ext_vector_type(4)));
typedef short s16x8 __attribute__((ext_vector_type(8)));
typedef float v2f   __attribute__((ext_vector_type(2)));

// f32 -> bf16 bits, round-to-nearest-even
__device__ __forceinline__ short bfr(float f) {
    unsigned int u = __float_as_uint(f);
    u += 0x7fffu + ((u >> 16) & 1u);
    return (short)(u >> 16);
}

// ---------------------------------------------------------------------------
// Block = (b, row p), 512 threads = 8 waves, (512,2), grid 512, XCD swizzle.
// Phase 1 via MFMA 16x16x32 bf16, per wave: c = w and w+8.
//   A[k][K]: lane row k = kt*16 + (l&15); elems {wy,wz,ww}/4 in j=0..2 of the
//     lane's K-group. B[K][q]: lane col q = qt*16 + (l&15); elems {x_pq, x_qp,
//     x_qq} in j=0..2. SYMMETRIC fill: all 4 K-groups carry the data once ->
//     D = 4 * (wy*r + wz*s + ww*d) with quarter-scaled weights = exact sum,
//     independent of lane->K-group mapping. C-init = a[k] = wx*x_pp + b1[k]
//     (q-invariant), read per (c,kt) as one float4 (rows (l>>4)*4+0..3).
//   Epilogue per tile: relu 4 regs + 8 fma (layer-2 dot, W2 from LDS float4
//     aligned to the same row pattern); k-reduce via shfl_xor 16/32.
// Diag: mask q==p, reduce over lanes 0..15. Phase 2: R16 verbatim.
// ---------------------------------------------------------------------------
__global__ __launch_bounds__(512, 2) void fused_rey(
    const float* __restrict__ x,
    const float* __restrict__ W1, const float* __restrict__ b1,
    const float* __restrict__ W2, const float* __restrict__ b2,
    const float* __restrict__ Wc, const float* __restrict__ bc,
    float* __restrict__ y)
{
    __shared__ float s_out[CCH][NN];    // 8 KB
    __shared__ float a_tab[CCH][HID];   // 8 KB
    __shared__ float w20t[HID];
    __shared__ float w21t[HID];
    __shared__ float s_diag[CCH];

    const int t    = threadIdx.x;
    const int bid0 = blockIdx.x;
    const int bid  = ((bid0 & 7) << 6) | (bid0 >> 3);   // XCD-contiguous
    const int p    = bid & 127;
    const int b    = bid >> 7;
    const int w    = t >> 6;            // wave 0..7
    const int l    = t & 63;
    const int lc   = l & 15;            // fast row/col index
    const float bb0 = b2[0], bb1 = b2[1];

    // ---- stage W2 tables + a-table ----
    if (t < HID) { w20t[t] = W2[t]; w21t[t] = W2[HID + t]; }
    #pragma unroll
    for (int i = 0; i < 4; ++i) {
        const int idx = t + 512 * i;
        const int cc = idx >> 7, k = idx & 127;
        const float xpp = x[(((size_t)(b * CCH + cc)) << 14) + p * (NN + 1)];
        a_tab[cc][k] = fmaf(W1[4 * k], xpp, b1[k]);
    }

    // ---- A fragments (static weights, quarter-scaled, symmetric fill) ----
    s16x8 afrag[8];
    #pragma unroll
    for (int kt = 0; kt < 8; ++kt) {
        const int k = kt * 16 + lc;
        afrag[kt] = (s16x8){ bfr(0.25f * W1[4 * k + 1]),
                             bfr(0.25f * W1[4 * k + 2]),
                             bfr(0.25f * W1[4 * k + 3]), 0, 0, 0, 0, 0 };
    }

    __syncthreads();

    #pragma unroll
    for (int c2 = 0; c2 < 2; ++c2) {
        const int c = w + 8 * c2;
        const float* xm = x + (((size_t)(b * CCH + c)) << 14);

        // B fragments: data for q = qt*16 + lc (symmetric fill)
        s16x8 bfrag[8];
        #pragma unroll
        for (int qt = 0; qt < 8; ++qt) {
            const int q = qt * 16 + lc;
            bfrag[qt] = (s16x8){ bfr(xm[p * NN + q]),
                                 bfr(xm[q * NN + p]),
                                 bfr(xm[q * (NN + 1)]), 0, 0, 0, 0, 0 };
        }

        float h0p[8], h1p[8];
        #pragma unroll
        for (int qt = 0; qt < 8; ++qt) { h0p[qt] = 0.f; h1p[qt] = 0.f; }

        #pragma unroll
        for (int kt = 0; kt < 8; ++kt) {
            const int kb = kt * 16 + 4 * (l >> 4);   // rows (l>>4)*4 + 0..3
            const float4 av  = *reinterpret_cast<const float4*>(&a_tab[c][kb]);
            const float4 s20 = *reinterpret_cast<const float4*>(&w20t[kb]);
            const float4 s21 = *reinterpret_cast<const float4*>(&w21t[kb]);
            f32x4 ci; ci[0] = av.x; ci[1] = av.y; ci[2] = av.z; ci[3] = av.w;

            #pragma unroll
            for (int qt = 0; qt < 8; ++qt) {
                f32x4 acc = __builtin_amdgcn_mfma_f32_16x16x32_bf16(
                                afrag[kt], bfrag[qt], ci, 0, 0, 0);
                const float u0 = fmaxf(acc[0], 0.f);
                const float u1 = fmaxf(acc[1], 0.f);
                const float u2 = fmaxf(acc[2], 0.f);
                const float u3 = fmaxf(acc[3], 0.f);
                float h0 = h0p[qt], h1 = h1p[qt];
                h0 = fmaf(s20.x, u0, h0); h1 = fmaf(s21.x, u0, h1);
                h0 = fmaf(s20.y, u1, h0); h1 = fmaf(s21.y, u1, h1);
                h0 = fmaf(s20.z, u2, h0); h1 = fmaf(s21.z, u2, h1);
                h0 = fmaf(s20.w, u3, h0); h1 = fmaf(s21.w, u3, h1);
                h0p[qt] = h0; h1p[qt] = h1;
            }
        }

        // reduce across the 4 k-lane-groups, write h1, accumulate diag
        float dsum = 0.f;
        #pragma unroll
        for (int qt = 0; qt < 8; ++qt) {
            float hq0 = h0p[qt], hq1 = h1p[qt];
            hq0 += __shfl_xor(hq0, 16); hq0 += __shfl_xor(hq0, 32);
            hq1 += __shfl_xor(hq1, 16); hq1 += __shfl_xor(hq1, 32);
            const int q = qt * 16 + lc;
            if (l < 16) s_out[c][q] = hq1 + bb1;
            dsum += (q == p) ? 0.f : hq0;
        }
        #pragma unroll
        for (int m = 8; m > 0; m >>= 1) dsum += __shfl_xor(dsum, m);
        if (l == 0) s_diag[c] = dsum * (1.0f / (NN - 1)) + bb0;
    }

    __syncthreads();
    if (t < CCH) s_out[t][p] = s_diag[t];
    __syncthreads();

    // ---- phase 2: y[b,d,p,:] = relu(sum_c s_out[c]*Wc[d][c] + bc[d]) ----
    const int wv = t >> 6;              // 0..7 -> 16 d's each
    const int m0 = l * 2;
    const v2f z2 = { 0.f, 0.f };
    v2f r[CCH];
    #pragma unroll
    for (int cc = 0; cc < CCH; ++cc)
        r[cc] = *reinterpret_cast<const v2f*>(&s_out[cc][m0]);

    #pragma unroll 4
    for (int dd = 0; dd < 16; ++dd) {
        const int d = wv * 16 + dd;         // wave-uniform
        const float bcv = bc[d];            // scalar load
        v2f acc = { bcv, bcv };
        #pragma unroll
        for (int cc = 0; cc < CCH; ++cc) {
            const float wcf = Wc[d * CCH + cc];   // scalar load
            acc = __builtin_elementwise_fma((v2f){ wcf, wcf }, r[cc], acc);
        }
        acc = __builtin_elementwise_max(acc, z2);
        *reinterpret_cast<v2f*>(
            &y[(((size_t)(b * DOUT + d)) * NN + p) * NN + m0]) = acc;
    }
}

extern "C" void kernel_launch(void* const* d_in, const int* in_sizes, int n_in,
                              void* d_out, int out_size, void* d_ws, size_t ws_size,
                              hipStream_t stream) {
    const float* x  = (const float*)d_in[0];
    const float* W1 = (const float*)d_in[1];
    const float* b1 = (const float*)d_in[2];
    const float* W2 = (const float*)d_in[3];
    const float* b2 = (const float*)d_in[4];
    const float* Wc = (const float*)d_in[5];
    const float* bc = (const float*)d_in[6];
    float* y = (float*)d_out;

    fused_rey<<<dim3(BB * NN), 512, 0, stream>>>(x, W1, b1, W2, b2, Wc, bc, y);
}

// Round 19
// 34.710 us; speedup vs baseline: 2.7416x; 2.7416x over previous
//
#include <hip/hip_runtime.h>

#define NN 128
#define CCH 16
#define BB 4
#define HID 128
#define DOUT 128

typedef float v2f __attribute__((ext_vector_type(2)));

// ---------------------------------------------------------------------------
// Single fused kernel (R16 structure; unroll depth + launch bounds relaxed).
// Block = (b, row p), 512 threads = 8 waves, grid 512. XCD swizzle kept.
// __launch_bounds__(512): no min-wave pressure -> allocator free (R15's
// squeeze-spill and R13's remat both avoided). #pragma unroll 8: 32 s_loads
// batched per wait -> longer VALU runs between lgkmcnt stalls.
//
// Phase 1: thread (c = t>>5, qg = t&31) owns channel c and FOUR q's
//   (two v2f pairs). Weights via wave-uniform s_load float4; a-term shared.
// Diag: mask q==p, width-32 shuffle. Phase 2: wave -> 16 d's, lane = m-pair.
// ---------------------------------------------------------------------------
__global__ __launch_bounds__(512) void fused_rey(
    const float* __restrict__ x,
    const float* __restrict__ W1, const float* __restrict__ b1,
    const float* __restrict__ W2, const float* __restrict__ b2,
    const float* __restrict__ Wc, const float* __restrict__ bc,
    float* __restrict__ y)
{
    __shared__ float s_out[CCH][NN];   // 8 KB
    __shared__ float s_diag[CCH];

    const int t    = threadIdx.x;
    const int bid0 = blockIdx.x;
    const int bid  = ((bid0 & 7) << 6) | (bid0 >> 3);   // XCD-contiguous (bijective)
    const int p    = bid & 127;
    const int b    = bid >> 7;
    const int c    = t >> 5;           // 0..15 (half-wave uniform)
    const int qg   = t & 31;
    const int q0   = qg * 4;           // q quad {q0..q0+3}

    const float* xm = x + (((size_t)(b * CCH + c)) << 14);

    // per-thread x loads (strided ones served by per-XCD L2 post-swizzle)
    const float4 vpq = *reinterpret_cast<const float4*>(&xm[p * NN + q0]);  // coalesced
    const v2f xpq01 = { vpq.x, vpq.y }, xpq23 = { vpq.z, vpq.w };
    const v2f xqp01 = { xm[q0 * NN + p],       xm[(q0 + 1) * NN + p] };
    const v2f xqp23 = { xm[(q0 + 2) * NN + p], xm[(q0 + 3) * NN + p] };
    const v2f xqq01 = { xm[q0 * (NN + 1)],       xm[(q0 + 1) * (NN + 1)] };
    const v2f xqq23 = { xm[(q0 + 2) * (NN + 1)], xm[(q0 + 3) * (NN + 1)] };
    const float xpp = xm[p * (NN + 1)];

    const float bb0 = b2[0], bb1 = b2[1];
    const v2f z2 = { 0.f, 0.f };
    v2f h0a = z2, h0b = z2, h1a = z2, h1b = z2;

    // ---- phase 1: hidden loop (v2f body, 4 cells/thread/k, unroll 8) ----
    #pragma unroll 8
    for (int k = 0; k < HID; ++k) {
        const float4 w  = reinterpret_cast<const float4*>(W1)[k];  // s_load_dwordx4
        const float b1k = b1[k];
        const float w20 = W2[k];
        const float w21 = W2[HID + k];
        const float a = fmaf(w.x, xpp, b1k);       // q-invariant, shared by 4 q's
        const v2f av  = { a, a };
        const v2f wy  = { w.y, w.y }, wz = { w.z, w.z }, ww = { w.w, w.w };
        const v2f w20v = { w20, w20 }, w21v = { w21, w21 };

        v2f hd0 = __builtin_elementwise_fma(wy, xpq01, av);
        hd0 = __builtin_elementwise_fma(wz, xqp01, hd0);
        hd0 = __builtin_elementwise_fma(ww, xqq01, hd0);
        hd0 = __builtin_elementwise_max(hd0, z2);
        h0a = __builtin_elementwise_fma(w20v, hd0, h0a);
        h1a = __builtin_elementwise_fma(w21v, hd0, h1a);

        v2f hd1 = __builtin_elementwise_fma(wy, xpq23, av);
        hd1 = __builtin_elementwise_fma(wz, xqp23, hd1);
        hd1 = __builtin_elementwise_fma(ww, xqq23, hd1);
        hd1 = __builtin_elementwise_max(hd1, z2);
        h0b = __builtin_elementwise_fma(w20v, hd1, h0b);
        h1b = __builtin_elementwise_fma(w21v, hd1, h1b);
    }

    // off-diagonal h1 (+b2[1]) -> LDS row c (16B store); (c,p) fixed after barrier
    float4 o;
    o.x = h1a[0] + bb1; o.y = h1a[1] + bb1;
    o.z = h1b[0] + bb1; o.w = h1b[1] + bb1;
    *reinterpret_cast<float4*>(&s_out[c][q0]) = o;

    // diag partial: mask q==p, reduce across the 32 lanes of this c
    float s = ((q0 == p)     ? 0.f : h0a[0]) + ((q0 + 1 == p) ? 0.f : h0a[1])
            + ((q0 + 2 == p) ? 0.f : h0b[0]) + ((q0 + 3 == p) ? 0.f : h0b[1]);
    #pragma unroll
    for (int off = 16; off > 0; off >>= 1)
        s += __shfl_down(s, off, 32);
    if (qg == 0) s_diag[c] = s * (1.0f / (NN - 1)) + bb0;

    __syncthreads();
    if (t < CCH) s_out[t][p] = s_diag[t];
    __syncthreads();

    // ---- phase 2: y[b,d,p,:] = relu(sum_c s_out[c]*Wc[d][c] + bc[d]) ----
    const int wv   = t >> 6;           // 0..7 -> 16 d's each (wave-uniform)
    const int lane = t & 63;
    const int m0   = lane * 2;
    v2f r[CCH];
    #pragma unroll
    for (int cc = 0; cc < CCH; ++cc)
        r[cc] = *reinterpret_cast<const v2f*>(&s_out[cc][m0]);

    #pragma unroll 4
    for (int dd = 0; dd < 16; ++dd) {
        const int d = wv * 16 + dd;        // wave-uniform
        const float bcv = bc[d];           // scalar load
        v2f acc = { bcv, bcv };
        #pragma unroll
        for (int cc = 0; cc < CCH; ++cc) {
            const float wcf = Wc[d * CCH + cc];   // scalar load
            acc = __builtin_elementwise_fma((v2f){ wcf, wcf }, r[cc], acc);
        }
        acc = __builtin_elementwise_max(acc, z2);
        *reinterpret_cast<v2f*>(
            &y[(((size_t)(b * DOUT + d)) * NN + p) * NN + m0]) = acc;
    }
}

extern "C" void kernel_launch(void* const* d_in, const int* in_sizes, int n_in,
                              void* d_out, int out_size, void* d_ws, size_t ws_size,
                              hipStream_t stream) {
    const float* x  = (const float*)d_in[0];
    const float* W1 = (const float*)d_in[1];
    const float* b1 = (const float*)d_in[2];
    const float* W2 = (const float*)d_in[3];
    const float* b2 = (const float*)d_in[4];
    const float* Wc = (const float*)d_in[5];
    const float* bc = (const float*)d_in[6];
    float* y = (float*)d_out;

    fused_rey<<<dim3(BB * NN), 512, 0, stream>>>(x, W1, b1, W2, b2, Wc, bc, y);
}